// Round 21
// baseline (188.500 us; speedup 1.0000x reference)
//
#include <hip/hip_runtime.h>
#include <stdint.h>

#define B_ 8
#define C_ 256
#define H_ 96
#define W_ 160
#define ND 9
#define NDISP 81
#define NCHUNK 128             // channel-pairs
#define TX 8
#define NXG 20
#define NTHR 256               // waves 0-2: consumers; wave 3: producer
#define NCOMP 180              // 9 dy * 20 xg
#define PBASE 192              // producer wave starts here
// Per-buffer f16-pair layout (bytes): in1 row: 160 words @0 (640 B);
// in2 row r(=dy): 168 words (x in [-4,164)) @ 640 + r*688. 688=43*16.
#define IN2_OFF 640
#define ROW_B 688
#define BUF_B 6912             // 640 + 9*688 = 6832, padded
#define NBUF 4                 // write-ahead-2 -> ONE barrier per chunk
#define NSEG 418               // uint4 segments: 40 in1 + 9*42 in2
#define HW (H_ * W_)
#define CHSTEP (2 * HW)        // channel-pair step

typedef __attribute__((ext_vector_type(2))) _Float16 half2v;

__device__ __forceinline__ unsigned pk(float lo, float hi) {
    return __builtin_bit_cast(unsigned, __builtin_amdgcn_cvt_pkrtz(lo, hi));
}
__device__ __forceinline__ float dot2acc(unsigned a, unsigned w, float acc) {
#if __has_builtin(__builtin_amdgcn_fdot2)
    return __builtin_amdgcn_fdot2(__builtin_bit_cast(half2v, a),
                                  __builtin_bit_cast(half2v, w), acc, false);
#else
    half2v av = __builtin_bit_cast(half2v, a);
    half2v wv = __builtin_bit_cast(half2v, w);
    return acc + (float)av.x * (float)wv.x + (float)av.y * (float)wv.y;
#endif
}

// uint4 segment s -> fp32 source (even-channel base) + LDS byte offset.
// Clamped cells hold finite garbage, masked at dot2/store time.
__device__ __forceinline__ const float* seg_src(int s, int b, int y,
        const float* in1, const float* in2, int* woff)
{
    if (s < 40) {                          // in1: x = 4s
        *woff = s * 16;
        return in1 + ((size_t)(b * C_) * H_ + y) * W_ + 4 * s;
    }
    const int t = s - 40;
    const int r = t / 42, k = t - r * 42;  // dy row, word-seg
    *woff = IN2_OFF + r * ROW_B + k * 16;
    int row = y + r - 4;
    row = row < 0 ? 0 : (row >= H_ ? H_ - 1 : row);      // clamp; masked later
    int x = 4 * k - 4;
    x = x < 0 ? 0 : (x > W_ - 4 ? W_ - 4 : x);           // clamp; masked later
    return in2 + ((size_t)(b * C_) * H_ + row) * W_ + x; // 16B-aligned
}

__global__ __launch_bounds__(NTHR) void corr_pc_kernel(
    const float* __restrict__ in1,
    const float* __restrict__ in2,
    float* __restrict__ out)
{
    __shared__ __align__(16) unsigned lds[NBUF * BUF_B / 4];   // 27648 B

    const int tid = threadIdx.x;
    const int b   = blockIdx.x & 7;       // XCD swizzle: batch pinned to XCD
    const int y   = blockIdx.x >> 3;
    const bool isProd = (tid >= PBASE);
    const int  pl = tid - PBASE;          // producer lane 0..63

    // ---- producer slots: lane pl owns segs pl + 64k, k=0..6 (448 >= 418)
    int of0=0, of1=0, of2=0, of3=0, of4=0, of5=0, of6=0;
    const float *q0=in1, *q1=in1, *q2=in1, *q3=in1, *q4=in1, *q5=in1, *q6=in1;
    bool v6 = false;                      // slots 0-5 always valid (384<418)
    if (isProd) {
        q0 = seg_src(pl,        b, y, in1, in2, &of0);
        q1 = seg_src(pl + 64,   b, y, in1, in2, &of1);
        q2 = seg_src(pl + 128,  b, y, in1, in2, &of2);
        q3 = seg_src(pl + 192,  b, y, in1, in2, &of3);
        q4 = seg_src(pl + 256,  b, y, in1, in2, &of4);
        q5 = seg_src(pl + 320,  b, y, in1, in2, &of5);
        v6 = (pl + 384) < NSEG;           // lanes 0..33
        if (v6) q6 = seg_src(pl + 384, b, y, in1, in2, &of6);
    }

    // ---- consumer coords (lanes 0..179): dy-major
    const bool isComp = (tid < NCOMP);
    const int  dy = isComp ? (tid / NXG) : 0;
    const int  xg = isComp ? (tid % NXG) : 0;
    const int  x0 = TX * xg;
    const bool rowOk = (y + dy - 4 >= 0) && (y + dy - 4 < H_);
    const bool mzW0 = (xg == 0);
    const bool mzW3 = (xg == NXG - 1);
    const int  aof = 32 * xg;
    const int  wof = IN2_OFF + dy * ROW_B + 32 * xg;

    float acc[ND][TX];
    #pragma unroll
    for (int dx = 0; dx < ND; ++dx)
        #pragma unroll
        for (int j = 0; j < TX; ++j) acc[dx][j] = 0.f;

    // producer staging regs, single set (slack = 1 full body; only the
    // producer wave carries the vmcnt wait — consumers never see it)
    float4 La0, La1, Lb0, Lb1, Lc0, Lc1, Ld0, Ld1, Le0, Le1, Lf0, Lf1, Lg0, Lg1;

    #define LOADS do {                                                        \
        La0 = *(const float4*)(q0); La1 = *(const float4*)(q0 + HW);          \
        Lb0 = *(const float4*)(q1); Lb1 = *(const float4*)(q1 + HW);          \
        Lc0 = *(const float4*)(q2); Lc1 = *(const float4*)(q2 + HW);          \
        Ld0 = *(const float4*)(q3); Ld1 = *(const float4*)(q3 + HW);          \
        Le0 = *(const float4*)(q4); Le1 = *(const float4*)(q4 + HW);          \
        Lf0 = *(const float4*)(q5); Lf1 = *(const float4*)(q5 + HW);          \
        Lg0 = *(const float4*)(q6); Lg1 = *(const float4*)(q6 + HW);          \
        q0 += CHSTEP; q1 += CHSTEP; q2 += CHSTEP; q3 += CHSTEP;               \
        q4 += CHSTEP; q5 += CHSTEP; q6 += CHSTEP;                             \
    } while (0);

    #define PKW(base, off, R0, R1)                                            \
        *(uint4*)((base) + (off)) = make_uint4(                               \
            pk(R0.x, R1.x), pk(R0.y, R1.y), pk(R0.z, R1.z), pk(R0.w, R1.w));

    #define CVTW(BUFI) do {                                                   \
        char* base = (char*)lds + (BUFI) * BUF_B;                             \
        PKW(base, of0, La0, La1)                                              \
        PKW(base, of1, Lb0, Lb1)                                              \
        PKW(base, of2, Lc0, Lc1)                                              \
        PKW(base, of3, Ld0, Ld1)                                              \
        PKW(base, of4, Le0, Le1)                                              \
        PKW(base, of5, Lf0, Lf1)                                              \
        if (v6) { PKW(base, of6, Lg0, Lg1) }                                  \
    } while (0);

    #define COMPUTE(BUFI)                                                     \
    if (isComp) {                                                             \
        const char* bb = (const char*)lds + (BUFI) * BUF_B;                   \
        uint4 A0 = *(const uint4*)(bb + aof);                                 \
        uint4 A1 = *(const uint4*)(bb + aof + 16);                            \
        uint4 W0 = *(const uint4*)(bb + wof);                                 \
        uint4 W1 = *(const uint4*)(bb + wof + 16);                            \
        uint4 W2 = *(const uint4*)(bb + wof + 32);                            \
        uint4 W3 = *(const uint4*)(bb + wof + 48);                            \
        if (mzW0) W0 = make_uint4(0u, 0u, 0u, 0u);                            \
        if (mzW3) W3 = make_uint4(0u, 0u, 0u, 0u);                            \
        unsigned a[8]  = {A0.x, A0.y, A0.z, A0.w, A1.x, A1.y, A1.z, A1.w};    \
        unsigned w[16] = {W0.x, W0.y, W0.z, W0.w, W1.x, W1.y, W1.z, W1.w,     \
                          W2.x, W2.y, W2.z, W2.w, W3.x, W3.y, W3.z, W3.w};    \
        _Pragma("unroll")                                                     \
        for (int dx = 0; dx < ND; ++dx) {                                     \
            _Pragma("unroll")                                                 \
            for (int j = 0; j < TX; ++j)                                      \
                acc[dx][j] = dot2acc(a[j], w[dx + j], acc[dx][j]);            \
        }                                                                     \
    }

    // body kc (buf kc&3): producer wave writes chunk kc+2 (regs loaded in
    // body kc-1) into buf (kc+2)&3 [consumers finished it 2 barriers ago],
    // then issues loads for kc+3. Consumer waves only read buf kc&3 + dot2.
    // ONE __syncthreads per chunk.
    #define BODY(KM4, DOW, DOL)                                               \
        if (isProd) {                                                         \
            if (DOW) { CVTW(((KM4) + 2) & 3) }                                \
            if (DOL) { LOADS }                                                \
        } else { COMPUTE(KM4) }                                               \
        __syncthreads();

    // ---- prologue (producer): c0->buf0, c1->buf1, c2 -> regs
    if (isProd) {
        LOADS              // c0
        CVTW(0)
        LOADS              // c1
        CVTW(1)
        LOADS              // c2
    }
    __syncthreads();

    // ---- main loop: kc = 0..123
    #pragma unroll 1
    for (int g = 0; g < 31; ++g) {
        BODY(0, true, true)
        BODY(1, true, true)
        BODY(2, true, true)
        BODY(3, true, true)
    }
    // ---- tail: kc = 124..127
    BODY(0, true, true)    // CVTW c126, LOADS c127
    BODY(1, true, false)   // CVTW c127
    BODY(2, false, false)
    BODY(3, false, false)

    #undef BODY
    #undef COMPUTE
    #undef CVTW
    #undef PKW
    #undef LOADS

    // ---- epilogue: OOB-dy rows output zeros via masked scale
    if (isComp) {
        const float m = rowOk ? (1.0f / (float)C_) : 0.f;
        float* outp = out + ((size_t)(b * NDISP + dy * ND) * H_ + y) * W_ + x0;
        #pragma unroll
        for (int dx = 0; dx < ND; ++dx) {
            float4 o0 = make_float4(acc[dx][0] * m, acc[dx][1] * m,
                                    acc[dx][2] * m, acc[dx][3] * m);
            float4 o1 = make_float4(acc[dx][4] * m, acc[dx][5] * m,
                                    acc[dx][6] * m, acc[dx][7] * m);
            *(float4*)(outp + dx * HW)     = o0;
            *(float4*)(outp + dx * HW + 4) = o1;
        }
    }
}

extern "C" void kernel_launch(void* const* d_in, const int* in_sizes, int n_in,
                              void* d_out, int out_size, void* d_ws, size_t ws_size,
                              hipStream_t stream) {
    const float* in1 = (const float*)d_in[0];
    const float* in2 = (const float*)d_in[1];
    float* out = (float*)d_out;

    const int grid = B_ * H_;   // 768 blocks (b, y)
    corr_pc_kernel<<<grid, NTHR, 0, stream>>>(in1, in2, out);
}

// Round 22
// 154.819 us; speedup vs baseline: 1.2176x; 1.2176x over previous
//
#include <hip/hip_runtime.h>
#include <stdint.h>

#define B_ 8
#define C_ 256
#define H_ 96
#define W_ 160
#define ND 9
#define NDISP 81
#define NCHUNK 128             // channel-pairs
#define TX 4
#define NXG 20                 // x-groups per half (80 = 20*4)
#define NTHR 256               // 4 waves
#define NCOMP 180              // 9 dy * 20 xg
// Per-buffer f16-pair layout (bytes): in1: 80 words @0 (320 B);
// in2 row r(=dy): 88 words (x in [80h-4, 80h+84)) @ 320 + r*352.
#define IN2_OFF 320
#define ROW_B 352              // 22*16
#define BUF_B 3584             // 3488 padded
#define NBUF 4                 // write-ahead-2 -> ONE barrier per chunk
#define NSEG 218               // uint4 segments/chunk: 20 in1 + 9*22 in2
#define HW (H_ * W_)
#define CHSTEP (2 * HW)        // channel-pair step

typedef __attribute__((ext_vector_type(2))) _Float16 half2v;

__device__ __forceinline__ unsigned pk(float lo, float hi) {
    return __builtin_bit_cast(unsigned, __builtin_amdgcn_cvt_pkrtz(lo, hi));
}
__device__ __forceinline__ float dot2acc(unsigned a, unsigned w, float acc) {
#if __has_builtin(__builtin_amdgcn_fdot2)
    return __builtin_amdgcn_fdot2(__builtin_bit_cast(half2v, a),
                                  __builtin_bit_cast(half2v, w), acc, false);
#else
    half2v av = __builtin_bit_cast(half2v, a);
    half2v wv = __builtin_bit_cast(half2v, w);
    return acc + (float)av.x * (float)wv.x + (float)av.y * (float)wv.y;
#endif
}

// uint4 segment s -> fp32 source (even-channel base) + LDS byte offset.
__device__ __forceinline__ const float* seg_src(int s, int b, int y, int h,
        const float* in1, const float* in2, int* woff)
{
    if (s < 20) {                          // in1: x = 80h + 4s (all real)
        *woff = s * 16;
        return in1 + ((size_t)(b * C_) * H_ + y) * W_ + 80 * h + 4 * s;
    }
    const int t = s - 20;
    const int r = t / 22, k = t - r * 22;  // dy row, word-seg
    *woff = IN2_OFF + r * ROW_B + k * 16;
    int row = y + r - 4;
    row = row < 0 ? 0 : (row >= H_ ? H_ - 1 : row);      // clamp; masked later
    int x = 80 * h - 4 + 4 * k;
    x = x < 0 ? 0 : (x > W_ - 4 ? W_ - 4 : x);           // clamp; masked later
    return in2 + ((size_t)(b * C_) * H_ + row) * W_ + x; // 16B-aligned
}

__global__ __launch_bounds__(NTHR) void corr_ra_kernel(
    const float* __restrict__ in1,
    const float* __restrict__ in2,
    float* __restrict__ out)
{
    __shared__ __align__(16) unsigned lds[NBUF * BUF_B / 4];   // 14336 B

    const int tid = threadIdx.x;
    const int b   = blockIdx.x & 7;       // XCD swizzle
    const int idx = blockIdx.x >> 3;      // 0..191
    const int y   = idx >> 1;
    const int h   = idx & 1;              // x half

    // ---- staging slot (1 per thread; invalid for tid >= 218)
    int w0off = 0;
    const bool v0 = tid < NSEG;
    const float* p0 = in1;                // safe dummy
    if (v0) p0 = seg_src(tid, b, y, h, in1, in2, &w0off);

    // ---- compute coords (lanes 0..179): dy-major
    const bool isComp = (tid < NCOMP);
    const int  dy = isComp ? (tid / NXG) : 0;
    const int  xg = isComp ? (tid % NXG) : 0;
    const int  x0 = 80 * h + TX * xg;
    const bool rowOk = (y + dy - 4 >= 0) && (y + dy - 4 < H_);
    const bool mzW0 = (h == 0) && (xg == 0);        // words x [-4,0)
    const bool mzW2 = (h == 1) && (xg == NXG - 1);  // words x [160,164)

    const int aof = 16 * xg;
    const int wof = IN2_OFF + dy * ROW_B + 16 * xg;

    float acc[ND][TX];
    #pragma unroll
    for (int dx = 0; dx < ND; ++dx)
        #pragma unroll
        for (int j = 0; j < TX; ++j) acc[dx][j] = 0.f;

    // staging register sets (letter-first suffixes — R17 pp-number lesson)
    float4 SAp0, SAp1;
    float4 SBp0, SBp1;
    // read-ahead register sets: P/Q, 4 uint4 each (rule #20: named)
    uint4 Pa, Pw0, Pw1, Pw2;
    uint4 Qa, Qw0, Qw1, Qw2;

    #define LOADS(S) do {                                                     \
        S##p0 = *(const float4*)(p0);  S##p1 = *(const float4*)(p0 + HW);     \
        p0 += CHSTEP;                                                         \
    } while (0);

    #define CVTW(BUFI, S) do {                                                \
        if (v0) {                                                             \
            char* base = (char*)lds + (BUFI) * BUF_B;                         \
            *(uint4*)(base + w0off) = make_uint4(                             \
                pk(S##p0.x, S##p1.x), pk(S##p0.y, S##p1.y),                   \
                pk(S##p0.z, S##p1.z), pk(S##p0.w, S##p1.w));                  \
        }                                                                     \
    } while (0);

    // read chunk in buf BUFI into regset R; masks applied once here
    #define RDNXT(BUFI, R)                                                    \
    if (isComp) {                                                             \
        const char* bb = (const char*)lds + (BUFI) * BUF_B;                   \
        R##a  = *(const uint4*)(bb + aof);                                    \
        R##w0 = *(const uint4*)(bb + wof);                                    \
        R##w1 = *(const uint4*)(bb + wof + 16);                               \
        R##w2 = *(const uint4*)(bb + wof + 32);                               \
        if (mzW0) R##w0 = make_uint4(0u, 0u, 0u, 0u);                         \
        if (mzW2) R##w2 = make_uint4(0u, 0u, 0u, 0u);                         \
    }

    #define DOT(R)                                                            \
    if (isComp) {                                                             \
        unsigned a[4]  = {R##a.x, R##a.y, R##a.z, R##a.w};                    \
        unsigned w[12] = {R##w0.x, R##w0.y, R##w0.z, R##w0.w,                 \
                          R##w1.x, R##w1.y, R##w1.z, R##w1.w,                 \
                          R##w2.x, R##w2.y, R##w2.z, R##w2.w};                \
        _Pragma("unroll")                                                     \
        for (int dx = 0; dx < ND; ++dx) {                                     \
            _Pragma("unroll")                                                 \
            for (int j = 0; j < TX; ++j)                                      \
                acc[dx][j] = dot2acc(a[j], w[dx + j], acc[dx][j]);            \
        }                                                                     \
    }

    // body kc (buf kc&3): issue ds_reads of chunk kc+1 (buffer valid since
    // body kc-1 + barrier) into RNX -- they overlap the dot2 burst on RCU
    // and the barrier's lgkm drain absorbs the tail; next body's dot2s see
    // zero LDS latency. Then CVTW kc+2 (regs from last body), LOADS kc+3.
    #define BODY(KM4, RNX, RCU, SW, SL, DOW, DOL)                             \
        RDNXT(((KM4) + 1) & 3, RNX)                                           \
        DOT(RCU)                                                              \
        if (DOW) { CVTW(((KM4) + 2) & 3, SW) }                                \
        if (DOL) { LOADS(SL) }                                                \
        __syncthreads();

    // ---- prologue: c0->buf0, c1->buf1 (via SA), c2 -> SB regs
    LOADS(SA)          // c0
    CVTW(0, SA)
    LOADS(SA)          // c1
    CVTW(1, SA)
    LOADS(SB)          // c2
    __syncthreads();
    RDNXT(0, P)        // chunk 0 -> P

    // ---- main loop: kc = 0..123 (even kc: compute P, read -> Q)
    #pragma unroll 1
    for (int g = 0; g < 31; ++g) {
        BODY(0, Q, P, SB, SA, true, true)
        BODY(1, P, Q, SA, SB, true, true)
        BODY(2, Q, P, SB, SA, true, true)
        BODY(3, P, Q, SA, SB, true, true)
    }
    // ---- tail: kc = 124..127
    BODY(0, Q, P, SB, SA, true, true)    // c126 written, c127 loaded -> SA
    BODY(1, P, Q, SA, SB, true, false)   // c127 written (buf3)
    BODY(2, Q, P, SA, SA, false, false)  // reads c127 -> Q, computes c126
    DOT(Q)                               // kc = 127

    #undef BODY
    #undef DOT
    #undef RDNXT
    #undef CVTW
    #undef LOADS

    // ---- epilogue: OOB-dy rows output zeros via masked scale
    if (isComp) {
        const float m = rowOk ? (1.0f / (float)C_) : 0.f;
        float* outp = out + ((size_t)(b * NDISP + dy * ND) * H_ + y) * W_ + x0;
        #pragma unroll
        for (int dx = 0; dx < ND; ++dx) {
            float4 o = make_float4(acc[dx][0] * m, acc[dx][1] * m,
                                   acc[dx][2] * m, acc[dx][3] * m);
            *(float4*)(outp + dx * HW) = o;
        }
    }
}

extern "C" void kernel_launch(void* const* d_in, const int* in_sizes, int n_in,
                              void* d_out, int out_size, void* d_ws, size_t ws_size,
                              hipStream_t stream) {
    const float* in1 = (const float*)d_in[0];
    const float* in2 = (const float*)d_in[1];
    float* out = (float*)d_out;

    const int grid = B_ * H_ * 2;   // 1536 blocks (b, y, half) = 6 per CU
    corr_ra_kernel<<<grid, NTHR, 0, stream>>>(in1, in2, out);
}

// Round 23
// 112.965 us; speedup vs baseline: 1.6687x; 1.3705x over previous
//
#include <hip/hip_runtime.h>
#include <stdint.h>

#define B_ 8
#define C_ 256
#define H_ 96
#define W_ 160
#define ND 9
#define NDISP 81
#define NCHUNK 128             // channel-pairs
#define TX 4
#define NXG 20                 // x-groups per half (80 = 20*4)
#define NTHR 256               // 4 waves
#define NCOMP 180              // 9 dy * 20 xg
// Per-buffer f16-pair layout (bytes): in1: 80 words @0 (320 B);
// in2 row r(=dy): 88 words (x in [80h-4, 80h+84)) @ 320 + r*352.
#define IN2_OFF 320
#define ROW_B 352              // 22*16
#define BUF_B 3584             // 3488 padded
#define NBUF 4                 // write-ahead-2 -> ONE barrier per chunk
#define NSEG 218               // uint4 segments/chunk: 20 in1 + 9*22 in2
#define HW (H_ * W_)
#define CHSTEP (2 * HW)        // channel-pair step

typedef __attribute__((ext_vector_type(2))) _Float16 half2v;

__device__ __forceinline__ unsigned pk(float lo, float hi) {
    return __builtin_bit_cast(unsigned, __builtin_amdgcn_cvt_pkrtz(lo, hi));
}
__device__ __forceinline__ float dot2acc(unsigned a, unsigned w, float acc) {
#if __has_builtin(__builtin_amdgcn_fdot2)
    return __builtin_amdgcn_fdot2(__builtin_bit_cast(half2v, a),
                                  __builtin_bit_cast(half2v, w), acc, false);
#else
    half2v av = __builtin_bit_cast(half2v, a);
    half2v wv = __builtin_bit_cast(half2v, w);
    return acc + (float)av.x * (float)wv.x + (float)av.y * (float)wv.y;
#endif
}

// Raw barrier: lgkmcnt(0) only (ds_write visibility). NO vmcnt drain —
// __syncthreads' vmcnt(0) put the global-load latency on every round's
// critical path (the 110 µs plateau's cause). Globals' waits are
// compiler-inserted at the CVTW use site, one body (~1600 cy) later.
__device__ __forceinline__ void block_barrier_lgkm() {
    asm volatile("s_waitcnt lgkmcnt(0)" ::: "memory");
    __builtin_amdgcn_s_barrier();
    asm volatile("" ::: "memory");
    __builtin_amdgcn_sched_barrier(0);   // no mem-op hoisting across barrier
}

// uint4 segment s -> fp32 source (even-channel base) + LDS byte offset.
__device__ __forceinline__ const float* seg_src(int s, int b, int y, int h,
        const float* in1, const float* in2, int* woff)
{
    if (s < 20) {                          // in1: x = 80h + 4s (all real)
        *woff = s * 16;
        return in1 + ((size_t)(b * C_) * H_ + y) * W_ + 80 * h + 4 * s;
    }
    const int t = s - 20;
    const int r = t / 22, k = t - r * 22;  // dy row, word-seg
    *woff = IN2_OFF + r * ROW_B + k * 16;
    int row = y + r - 4;
    row = row < 0 ? 0 : (row >= H_ ? H_ - 1 : row);      // clamp; masked later
    int x = 80 * h - 4 + 4 * k;
    x = x < 0 ? 0 : (x > W_ - 4 ? W_ - 4 : x);           // clamp; masked later
    return in2 + ((size_t)(b * C_) * H_ + row) * W_ + x; // 16B-aligned
}

__global__ __launch_bounds__(NTHR) void corr_rb_kernel(
    const float* __restrict__ in1,
    const float* __restrict__ in2,
    float* __restrict__ out)
{
    __shared__ __align__(16) unsigned lds[NBUF * BUF_B / 4];   // 14336 B

    const int tid = threadIdx.x;
    const int b   = blockIdx.x & 7;       // XCD swizzle
    const int idx = blockIdx.x >> 3;      // 0..191
    const int y   = idx >> 1;
    const int h   = idx & 1;              // x half

    // ---- staging slot (1 per thread; invalid for tid >= 218)
    int w0off = 0;
    const bool v0 = tid < NSEG;
    const float* p0 = in1;                // safe dummy
    if (v0) p0 = seg_src(tid, b, y, h, in1, in2, &w0off);

    // ---- compute coords (lanes 0..179): dy-major
    const bool isComp = (tid < NCOMP);
    const int  dy = isComp ? (tid / NXG) : 0;
    const int  xg = isComp ? (tid % NXG) : 0;
    const int  x0 = 80 * h + TX * xg;
    const bool rowOk = (y + dy - 4 >= 0) && (y + dy - 4 < H_);
    const bool mzW0 = (h == 0) && (xg == 0);        // words x [-4,0)
    const bool mzW2 = (h == 1) && (xg == NXG - 1);  // words x [160,164)

    const int aof = 16 * xg;                         // in1 words [4xg, 4xg+4)
    const int wof = IN2_OFF + dy * ROW_B + 16 * xg;  // in2 words [4xg-4,4xg+8)

    float acc[ND][TX];
    #pragma unroll
    for (int dx = 0; dx < ND; ++dx)
        #pragma unroll
        for (int j = 0; j < TX; ++j) acc[dx][j] = 0.f;

    // staging register sets (letter-first suffixes — R17 pp-number lesson)
    float4 SAp0, SAp1;
    float4 SBp0, SBp1;

    #define LOADS(S) do {                                                     \
        S##p0 = *(const float4*)(p0);  S##p1 = *(const float4*)(p0 + HW);     \
        p0 += CHSTEP;                                                         \
    } while (0);

    #define CVTW(BUFI, S) do {                                                \
        if (v0) {                                                             \
            char* base = (char*)lds + (BUFI) * BUF_B;                         \
            *(uint4*)(base + w0off) = make_uint4(                             \
                pk(S##p0.x, S##p1.x), pk(S##p0.y, S##p1.y),                   \
                pk(S##p0.z, S##p1.z), pk(S##p0.w, S##p1.w));                  \
        }                                                                     \
    } while (0);

    #define COMPUTE(BUFI)                                                     \
    if (isComp) {                                                             \
        const char* bb = (const char*)lds + (BUFI) * BUF_B;                   \
        uint4 A0 = *(const uint4*)(bb + aof);                                 \
        uint4 W0 = *(const uint4*)(bb + wof);                                 \
        uint4 W1 = *(const uint4*)(bb + wof + 16);                            \
        uint4 W2 = *(const uint4*)(bb + wof + 32);                            \
        if (mzW0) W0 = make_uint4(0u, 0u, 0u, 0u);                            \
        if (mzW2) W2 = make_uint4(0u, 0u, 0u, 0u);                            \
        unsigned a[4]  = {A0.x, A0.y, A0.z, A0.w};                            \
        unsigned w[12] = {W0.x, W0.y, W0.z, W0.w, W1.x, W1.y, W1.z, W1.w,     \
                          W2.x, W2.y, W2.z, W2.w};                            \
        _Pragma("unroll")                                                     \
        for (int dx = 0; dx < ND; ++dx) {                                     \
            _Pragma("unroll")                                                 \
            for (int j = 0; j < TX; ++j)                                      \
                acc[dx][j] = dot2acc(a[j], w[dx + j], acc[dx][j]);            \
        }                                                                     \
    }

    // body kc (buf kc&3): CVTW chunk kc+2 (regs loaded last body; vmcnt wait
    // compiler-inserted HERE, one body after issue -> hidden) into buf
    // (kc+2)&3; LOADS kc+3 (no wait until next body); COMPUTE kc; raw
    // barrier with lgkm-only drain.
    #define BODY(KM4, SWR, SLD, DOW, DOL)                                     \
        if (DOW) { CVTW(((KM4) + 2) & 3, SWR) }                               \
        if (DOL) { LOADS(SLD) }                                               \
        COMPUTE(KM4)                                                          \
        block_barrier_lgkm();

    // ---- prologue: c0->buf0, c1->buf1 (via SA), c2 -> SB regs
    LOADS(SA)          // c0
    CVTW(0, SA)
    LOADS(SA)          // c1
    CVTW(1, SA)
    LOADS(SB)          // c2
    block_barrier_lgkm();

    // ---- main loop: kc = 0..123
    #pragma unroll 1
    for (int g = 0; g < 31; ++g) {
        BODY(0, SB, SA, true, true)
        BODY(1, SA, SB, true, true)
        BODY(2, SB, SA, true, true)
        BODY(3, SA, SB, true, true)
    }
    // ---- tail: kc = 124..127
    BODY(0, SB, SA, true, true)    // writes c126, loads c127 -> SA
    BODY(1, SA, SB, true, false)   // writes c127
    BODY(2, SA, SA, false, false)
    BODY(3, SA, SA, false, false)

    #undef BODY
    #undef COMPUTE
    #undef CVTW
    #undef LOADS

    // ---- epilogue: OOB-dy rows output zeros via masked scale
    if (isComp) {
        const float m = rowOk ? (1.0f / (float)C_) : 0.f;
        float* outp = out + ((size_t)(b * NDISP + dy * ND) * H_ + y) * W_ + x0;
        #pragma unroll
        for (int dx = 0; dx < ND; ++dx) {
            float4 o = make_float4(acc[dx][0] * m, acc[dx][1] * m,
                                   acc[dx][2] * m, acc[dx][3] * m);
            *(float4*)(outp + dx * HW) = o;
        }
    }
}

extern "C" void kernel_launch(void* const* d_in, const int* in_sizes, int n_in,
                              void* d_out, int out_size, void* d_ws, size_t ws_size,
                              hipStream_t stream) {
    const float* in1 = (const float*)d_in[0];
    const float* in2 = (const float*)d_in[1];
    float* out = (float*)d_out;

    const int grid = B_ * H_ * 2;   // 1536 blocks (b, y, half) = 6 per CU
    corr_rb_kernel<<<grid, NTHR, 0, stream>>>(in1, in2, out);
}